// Round 15
// baseline (393.176 us; speedup 1.0000x reference)
//
#include <hip/hip_runtime.h>
#include <hip/hip_bf16.h>

#define NTOK 2048   // B*S
#define HD   1024
#define FD   3584
#define NE   8

#define BM 128              // gemm1 m-tile
#define BN1 64              // gemm1 f-tile
#define BM2 64              // gemm2 m-tile
#define BN 128              // gemm2 h-tile
#define BK 64               // 128B LDS rows (verified conflict-free fragment reads)
#define NIT1 (HD / BK)      // 16
#define KS2 2               // gemm2 K-split
#define KLEN2 (FD / KS2)    // 1792
#define NIT2 (KLEN2 / BK)   // 28

typedef __attribute__((ext_vector_type(8))) short short8;
typedef __attribute__((ext_vector_type(4))) float f32x4;

__device__ __forceinline__ unsigned short f2bf(float f) {
    __hip_bfloat16 h = __float2bfloat16(f);
    union { __hip_bfloat16 h; unsigned short u; } c; c.h = h;
    return c.u;
}

// global_load_lds width=16: per-lane 16B global src -> wave-uniform LDS base + lane*16
typedef __attribute__((address_space(1))) const unsigned int g_cu32;
typedef __attribute__((address_space(3))) unsigned int l_u32;
__device__ __forceinline__ void gl16(const void* g, void* l) {
    __builtin_amdgcn_global_load_lds((g_cu32*)g, (l_u32*)(unsigned int)(size_t)l, 16, 0, 0);
}

// ---------------- router: fp32 logits, softmax, top-2, renorm ----------------
__global__ void k_router(const float* __restrict__ x, const float* __restrict__ gw,
                         int* __restrict__ sel, float* __restrict__ selw,
                         int* __restrict__ counts) {
    int token = blockIdx.x * 4 + (threadIdx.x >> 6);
    int lane  = threadIdx.x & 63;
    if (token >= NTOK) return;
    const float* xr = x + (size_t)token * HD;
    float acc[NE];
#pragma unroll
    for (int e = 0; e < NE; e++) acc[e] = 0.f;
    for (int h = lane; h < HD; h += 64) {
        float xv = xr[h];
        const float4* g = (const float4*)(gw + (size_t)h * NE);
        float4 g0 = g[0], g1 = g[1];
        acc[0] += xv * g0.x; acc[1] += xv * g0.y; acc[2] += xv * g0.z; acc[3] += xv * g0.w;
        acc[4] += xv * g1.x; acc[5] += xv * g1.y; acc[6] += xv * g1.z; acc[7] += xv * g1.w;
    }
#pragma unroll
    for (int e = 0; e < NE; e++) {
#pragma unroll
        for (int off = 32; off >= 1; off >>= 1) acc[e] += __shfl_xor(acc[e], off, 64);
    }
    if (lane == 0) {
        float m = acc[0];
#pragma unroll
        for (int e = 1; e < NE; e++) m = fmaxf(m, acc[e]);
        float z[NE];
#pragma unroll
        for (int e = 0; e < NE; e++) z[e] = expf(acc[e] - m);
        int e0 = 0; float z0 = z[0];
#pragma unroll
        for (int e = 1; e < NE; e++) if (z[e] > z0) { z0 = z[e]; e0 = e; }
        int e1 = -1; float z1 = -1.f;
#pragma unroll
        for (int e = 0; e < NE; e++) if (e != e0 && z[e] > z1) { z1 = z[e]; e1 = e; }
        float s = z0 + z1;
        sel[token * 2 + 0] = e0; sel[token * 2 + 1] = e1;
        selw[token * 2 + 0] = z0 / s; selw[token * 2 + 1] = z1 / s;
        atomicAdd(&counts[e0], 1);
        atomicAdd(&counts[e1], 1);
    }
}

__global__ void k_scan(const int* __restrict__ counts, int* __restrict__ basep,
                       int* __restrict__ fillc) {
    if (threadIdx.x == 0 && blockIdx.x == 0) {
        int b = 0;
        for (int e = 0; e < NE; e++) { basep[e] = b; b += counts[e]; fillc[e] = 0; }
    }
}

__global__ void k_fill(const int* __restrict__ sel, const float* __restrict__ selw,
                       const int* __restrict__ basep, int* __restrict__ fillc,
                       int* __restrict__ rowmap, int* __restrict__ rowk,
                       float* __restrict__ roww) {
    int n = blockIdx.x * blockDim.x + threadIdx.x;
    if (n >= NTOK) return;
#pragma unroll
    for (int k = 0; k < 2; k++) {
        int e = sel[n * 2 + k];
        int p = atomicAdd(&fillc[e], 1);
        int g = basep[e] + p;
        rowmap[g] = n; rowk[g] = k; roww[g] = selw[n * 2 + k];
    }
}

// ---------------- x -> bf16 ----------------
__global__ void k_cvt(const float* __restrict__ x, unsigned short* __restrict__ xb) {
    size_t i = ((size_t)blockIdx.x * blockDim.x + threadIdx.x) * 8;
    float4 a = *(const float4*)(x + i);
    float4 b = *(const float4*)(x + i + 4);
    unsigned short p[8] __attribute__((aligned(16))) =
        { f2bf(a.x), f2bf(a.y), f2bf(a.z), f2bf(a.w),
          f2bf(b.x), f2bf(b.y), f2bf(b.z), f2bf(b.w) };
    *(uint4*)(xb + i) = *(uint4*)p;
}

// ---------------- GEMM1: reads w1/w3 fp32 DIRECTLY (no transpose pass) ----------------
// A (xb bf16): gload_lds with pre-swizzled source, as verified in r7-r13.
// B (w1/w3 fp32 [K][N]): reg-staged. Thread (nq=t&15, kd=t>>4) loads 4 k-rows x
// float4 (coalesced 256B runs along N), converts, packs k-pairs, and writes
// 2x ds_write_b64 per n into the SAME swizzled layout the fragment reads expect:
//   word = n*32 + 4*((kd>>1)^(n&7)) + 2*(kd&1); chunk L stored at L^(n&7).
// Read side unchanged: kc = (kk*32+lhi*8) ^ ((l15&7)*8)  (chunk-level XOR).
// Pipeline: issue t+1 loads -> MFMA(t) -> write t+1 (compiler waits on reg use)
// -> vmcnt(0) for A-gloads -> one barrier.
__global__ __launch_bounds__(256, 2) void k_gemm1(
    const unsigned short* __restrict__ xb,
    const float* __restrict__ w1, const float* __restrict__ w3,
    const int* __restrict__ counts, const int* __restrict__ basep,
    const int* __restrict__ rowmap, unsigned short* __restrict__ act)
{
    const int e = blockIdx.z;
    const int nrows = counts[e];
    const int m0 = blockIdx.y * BM;
    if (m0 >= nrows) return;
    const int f0 = blockIdx.x * BN1;
    const int gbase = basep[e];

    __shared__ __align__(16) unsigned short At[2][BM][BK];
    __shared__ __align__(16) unsigned short B1[2][BN1][BK];
    __shared__ __align__(16) unsigned short B3[2][BN1][BK];

    const int t = threadIdx.x;
    const int lane = t & 63;
    const int w = t >> 6;                 // 0..3
    const int wrm = w >> 1, wnn = w & 1;  // 2x2 wave grid; wave tile 64 x 32
    const int lr = lane >> 3;
    const int so = ((lane & 7) ^ lr) * 8; // A staging pre-swizzle

    const unsigned short* asrc[4];
#pragma unroll
    for (int c = 0; c < 4; c++) {
        const int row = (w * 4 + c) * 8 + lr;
        const int tok = rowmap[gbase + min(m0 + row, nrows - 1)];
        asrc[c] = xb + (size_t)tok * HD + so;
    }

    const int nq = t & 15;                // n-quad 0..15
    const int kd = t >> 4;                // 0..15, covers k-rows 4kd..4kd+3
    const float* b1p = w1 + (size_t)e * HD * FD + (size_t)(4 * kd) * FD + f0 + 4 * nq;
    const float* b3p = w3 + (size_t)e * HD * FD + (size_t)(4 * kd) * FD + f0 + 4 * nq;
    unsigned int* const b1w = (unsigned int*)&B1[0][0][0];
    unsigned int* const b3w = (unsigned int*)&B3[0][0][0];
    const int BUFW = BN1 * BK / 2;        // 2048 u32 words per buffer

    f32x4 acc1[4][2], acc3[4][2];
#pragma unroll
    for (int i = 0; i < 4; i++)
#pragma unroll
        for (int j = 0; j < 2; j++) { acc1[i][j] = (f32x4)(0.f); acc3[i][j] = (f32x4)(0.f); }

    const int l15 = lane & 15;
    const int lhi = lane >> 4;
    const int rs = (l15 & 7) * 8;

    float4 b1v[4], b3v[4];

#define G1_WRITE_B(buf_) do {                                                   \
    _Pragma("unroll")                                                           \
    for (int c = 0; c < 4; c++) {                                               \
        const int n = 4 * nq + c;                                               \
        const int wi = n * 32 + 4 * ((kd >> 1) ^ (n & 7)) + 2 * (kd & 1);       \
        uint2 u;                                                                \
        u.x = (unsigned int)f2bf(((const float*)&b1v[0])[c])                    \
            | ((unsigned int)f2bf(((const float*)&b1v[1])[c]) << 16);           \
        u.y = (unsigned int)f2bf(((const float*)&b1v[2])[c])                    \
            | ((unsigned int)f2bf(((const float*)&b1v[3])[c]) << 16);           \
        *(uint2*)&b1w[(buf_) * BUFW + wi] = u;                                  \
        uint2 v;                                                                \
        v.x = (unsigned int)f2bf(((const float*)&b3v[0])[c])                    \
            | ((unsigned int)f2bf(((const float*)&b3v[1])[c]) << 16);           \
        v.y = (unsigned int)f2bf(((const float*)&b3v[2])[c])                    \
            | ((unsigned int)f2bf(((const float*)&b3v[3])[c]) << 16);           \
        *(uint2*)&b3w[(buf_) * BUFW + wi] = v;                                  \
    }                                                                           \
} while (0)

    // prologue: tile 0
#pragma unroll
    for (int r = 0; r < 4; r++) b1v[r] = *(const float4*)(b1p + (size_t)r * FD);
#pragma unroll
    for (int r = 0; r < 4; r++) b3v[r] = *(const float4*)(b3p + (size_t)r * FD);
#pragma unroll
    for (int c = 0; c < 4; c++) gl16(asrc[c], &At[0][(w * 4 + c) * 8][0]);
    G1_WRITE_B(0);
    asm volatile("s_waitcnt vmcnt(0)" ::: "memory");
    __builtin_amdgcn_s_barrier();

    for (int it = 0; it < NIT1; ++it) {
        const int cur = it & 1;
        const bool more = (it + 1 < NIT1);
        if (more) {
            const size_t k0 = (size_t)(it + 1) * BK;
#pragma unroll
            for (int r = 0; r < 4; r++) b1v[r] = *(const float4*)(b1p + (k0 + r) * FD);
#pragma unroll
            for (int r = 0; r < 4; r++) b3v[r] = *(const float4*)(b3p + (k0 + r) * FD);
#pragma unroll
            for (int c = 0; c < 4; c++) gl16(asrc[c] + k0, &At[cur ^ 1][(w * 4 + c) * 8][0]);
        }
#pragma unroll
        for (int kk = 0; kk < 2; kk++) {
            const int kc = (kk * 32 + lhi * 8) ^ rs;
            short8 af[4], b1f[2], b3f[2];
#pragma unroll
            for (int i = 0; i < 4; i++)
                af[i] = *(const short8*)&At[cur][wrm * 64 + i * 16 + l15][kc];
#pragma unroll
            for (int j = 0; j < 2; j++) {
                b1f[j] = *(const short8*)&B1[cur][wnn * 32 + j * 16 + l15][kc];
                b3f[j] = *(const short8*)&B3[cur][wnn * 32 + j * 16 + l15][kc];
            }
#pragma unroll
            for (int i = 0; i < 4; i++)
#pragma unroll
                for (int j = 0; j < 2; j++) {
                    acc1[i][j] = __builtin_amdgcn_mfma_f32_16x16x32_bf16(af[i], b1f[j], acc1[i][j], 0, 0, 0);
                    acc3[i][j] = __builtin_amdgcn_mfma_f32_16x16x32_bf16(af[i], b3f[j], acc3[i][j], 0, 0, 0);
                }
        }
        if (more) {
            G1_WRITE_B(cur ^ 1);                               // compiler waits on b1v/b3v
            asm volatile("s_waitcnt vmcnt(0)" ::: "memory");   // A gloads landed
        }
        __builtin_amdgcn_s_barrier();
    }

    // epilogue: SwiGLU, bf16 act
    const int rbase = wrm * 64 + lhi * 4;
    const int cbase = f0 + wnn * 32 + l15;
#pragma unroll
    for (int i = 0; i < 4; i++) {
#pragma unroll
        for (int r = 0; r < 4; r++) {
            const int ml = rbase + i * 16 + r;
            if (m0 + ml < nrows) {
                const size_t rowoff = (size_t)(gbase + m0 + ml) * FD;
#pragma unroll
                for (int j = 0; j < 2; j++) {
                    float y1 = acc1[i][j][r];
                    float y3 = acc3[i][j][r];
                    float sv = (y1 / (1.f + __expf(-y1))) * y3;
                    act[rowoff + cbase + j * 16] = f2bf(sv);
                }
            }
        }
    }
#undef G1_WRITE_B
}

// ---------------- GEMM2: reads w2 fp32 DIRECTLY; BM2=64 x BN=128, K-split x2 ----------------
// Same reg-staged B scheme: thread (nq=t&31, kd8=t>>5) handles kd in {kd8, kd8+8},
// 8 float4 loads (512B runs along N=HD), 8 ds_write_b64 swizzle-compatible writes.
__global__ __launch_bounds__(256, 3) void k_gemm2(
    const unsigned short* __restrict__ act,
    const float* __restrict__ w2,
    const int* __restrict__ counts, const int* __restrict__ basep,
    const int* __restrict__ rowmap, const int* __restrict__ rowk,
    const float* __restrict__ roww, float* __restrict__ partial)
{
    const int z = blockIdx.z;
    const int e = z >> 1, ks = z & 1;
    const int nrows = counts[e];
    const int m0 = blockIdx.y * BM2;
    if (m0 >= nrows) return;
    const int h0 = blockIdx.x * BN;
    const int gbase = basep[e];
    const int kbase = ks * KLEN2;

    __shared__ __align__(16) unsigned short At[2][BM2][BK];
    __shared__ __align__(16) unsigned short Bt[2][BN][BK];

    const int t = threadIdx.x;
    const int lane = t & 63;
    const int w = t >> 6;                 // 0..3
    const int wr2 = w >> 1, wn2 = w & 1;  // 2x2; wave tile 32 x 64
    const int lr = lane >> 3;
    const int so = ((lane & 7) ^ lr) * 8;

    const unsigned short* asrc[2];
#pragma unroll
    for (int c = 0; c < 2; c++) {
        const int row = (w * 2 + c) * 8 + lr;
        asrc[c] = act + ((size_t)gbase + min(m0 + row, nrows - 1)) * FD + so + kbase;
    }

    const int nq = t & 31;                // n-quad 0..31
    const int kd8 = t >> 5;               // 0..7; thread covers kd = kd8, kd8+8
    const float* bp = w2 + (size_t)e * FD * HD + (size_t)(kbase + 4 * kd8) * HD + h0 + 4 * nq;
    unsigned int* const btw = (unsigned int*)&Bt[0][0][0];
    const int BUFW2 = BN * BK / 2;        // 4096 u32 words per buffer

    f32x4 acc[2][4];
#pragma unroll
    for (int i = 0; i < 2; i++)
#pragma unroll
        for (int j = 0; j < 4; j++) acc[i][j] = (f32x4)(0.f);

    const int l15 = lane & 15;
    const int lhi = lane >> 4;
    const int rs = (l15 & 7) * 8;

    float4 bv[2][4];

#define G2_WRITE_B(buf_) do {                                                   \
    _Pragma("unroll")                                                           \
    for (int s = 0; s < 2; s++) {                                               \
        const int kdv = kd8 + 8 * s;                                            \
        _Pragma("unroll")                                                       \
        for (int c = 0; c < 4; c++) {                                           \
            const int n = 4 * nq + c;                                           \
            const int wi = n * 32 + 4 * ((kdv >> 1) ^ (n & 7)) + 2 * (kdv & 1); \
            uint2 u;                                                            \
            u.x = (unsigned int)f2bf(((const float*)&bv[s][0])[c])              \
                | ((unsigned int)f2bf(((const float*)&bv[s][1])[c]) << 16);     \
            u.y = (unsigned int)f2bf(((const float*)&bv[s][2])[c])              \
                | ((unsigned int)f2bf(((const float*)&bv[s][3])[c]) << 16);     \
            *(uint2*)&btw[(buf_) * BUFW2 + wi] = u;                             \
        }                                                                       \
    }                                                                           \
} while (0)

    // prologue: tile 0
#pragma unroll
    for (int s = 0; s < 2; s++)
#pragma unroll
        for (int r = 0; r < 4; r++)
            bv[s][r] = *(const float4*)(bp + (size_t)(32 * s + r) * HD);
#pragma unroll
    for (int c = 0; c < 2; c++) gl16(asrc[c], &At[0][(w * 2 + c) * 8][0]);
    G2_WRITE_B(0);
    asm volatile("s_waitcnt vmcnt(0)" ::: "memory");
    __builtin_amdgcn_s_barrier();

    for (int it = 0; it < NIT2; ++it) {
        const int cur = it & 1;
        const bool more = (it + 1 < NIT2);
        if (more) {
            const size_t k0 = (size_t)(it + 1) * BK;
#pragma unroll
            for (int s = 0; s < 2; s++)
#pragma unroll
                for (int r = 0; r < 4; r++)
                    bv[s][r] = *(const float4*)(bp + (k0 + 32 * s + r) * HD);
#pragma unroll
            for (int c = 0; c < 2; c++) gl16(asrc[c] + k0, &At[cur ^ 1][(w * 2 + c) * 8][0]);
        }
#pragma unroll
        for (int kk = 0; kk < 2; kk++) {
            const int kc = (kk * 32 + lhi * 8) ^ rs;
            short8 af[2], bf[4];
#pragma unroll
            for (int i = 0; i < 2; i++)
                af[i] = *(const short8*)&At[cur][wr2 * 32 + i * 16 + l15][kc];
#pragma unroll
            for (int j = 0; j < 4; j++)
                bf[j] = *(const short8*)&Bt[cur][wn2 * 64 + j * 16 + l15][kc];
#pragma unroll
            for (int i = 0; i < 2; i++)
#pragma unroll
                for (int j = 0; j < 4; j++)
                    acc[i][j] = __builtin_amdgcn_mfma_f32_16x16x32_bf16(af[i], bf[j], acc[i][j], 0, 0, 0);
        }
        if (more) {
            G2_WRITE_B(cur ^ 1);
            asm volatile("s_waitcnt vmcnt(0)" ::: "memory");
        }
        __builtin_amdgcn_s_barrier();
    }

    const int rbase = wr2 * 32 + lhi * 4;
    const int cbase = h0 + wn2 * 64 + l15;
#pragma unroll
    for (int i = 0; i < 2; i++) {
#pragma unroll
        for (int r = 0; r < 4; r++) {
            const int ml = rbase + i * 16 + r;
            if (m0 + ml < nrows) {
                const int grow = gbase + m0 + ml;
                const int tok = rowmap[grow];
                const int slot = rowk[grow];
                const float wv = roww[grow];
                float* op = partial + (((size_t)slot * KS2 + ks) * NTOK + tok) * HD + cbase;
#pragma unroll
                for (int j = 0; j < 4; j++) op[j * 16] = acc[i][j][r] * wv;
            }
        }
    }
#undef G2_WRITE_B
}

__global__ void k_combine(const float* __restrict__ partial, float* __restrict__ out) {
    size_t i = ((size_t)blockIdx.x * blockDim.x + threadIdx.x) * 4;
    const size_t st = (size_t)NTOK * HD;
    float4 o = *(const float4*)(partial + i);
#pragma unroll
    for (int s = 1; s < 2 * KS2; s++) {
        float4 v = *(const float4*)(partial + (size_t)s * st + i);
        o.x += v.x; o.y += v.y; o.z += v.z; o.w += v.w;
    }
    *(float4*)(out + i) = o;
}

extern "C" void kernel_launch(void* const* d_in, const int* in_sizes, int n_in,
                              void* d_out, int out_size, void* d_ws, size_t ws_size,
                              hipStream_t stream) {
    const float* x  = (const float*)d_in[0];
    const float* gw = (const float*)d_in[1];
    const float* w1 = (const float*)d_in[2];
    const float* w3 = (const float*)d_in[3];
    const float* w2 = (const float*)d_in[4];
    float* out = (float*)d_out;

    char* ws = (char*)d_ws;
    size_t off = 0;
    auto alloc = [&](size_t b) { char* p = ws + off; off += (b + 255) & ~(size_t)255; return p; };
    int*   sel    = (int*)  alloc((size_t)NTOK * 2 * 4);
    float* selw   = (float*)alloc((size_t)NTOK * 2 * 4);
    int*   counts = (int*)  alloc(NE * 4);
    int*   basep  = (int*)  alloc(NE * 4);
    int*   fillc  = (int*)  alloc(NE * 4);
    int*   rowmap = (int*)  alloc((size_t)NTOK * 2 * 4);
    int*   rowk   = (int*)  alloc((size_t)NTOK * 2 * 4);
    float* roww   = (float*)alloc((size_t)NTOK * 2 * 4);
    unsigned short* xb  = (unsigned short*)alloc((size_t)NTOK * HD * 2);
    unsigned short* act = (unsigned short*)alloc((size_t)NTOK * 2 * FD * 2);
    float* partial = (float*)alloc((size_t)2 * KS2 * NTOK * HD * 4);

    hipMemsetAsync(counts, 0, NE * 4, stream);
    k_cvt<<<(NTOK * HD) / (256 * 8), 256, 0, stream>>>(x, xb);
    k_router<<<NTOK / 4, 256, 0, stream>>>(x, gw, sel, selw, counts);
    k_scan<<<1, 64, 0, stream>>>(counts, basep, fillc);
    k_fill<<<NTOK / 256, 256, 0, stream>>>(sel, selw, basep, fillc, rowmap, rowk, roww);
    k_gemm1<<<dim3(FD / BN1, NTOK / BM, NE), 256, 0, stream>>>(xb, w1, w3, counts, basep, rowmap, act);
    k_gemm2<<<dim3(HD / BN, NTOK / BM2, NE * KS2), 256, 0, stream>>>(act, w2, counts, basep, rowmap, rowk, roww, partial);
    k_combine<<<(NTOK * HD) / (256 * 4), 256, 0, stream>>>(partial, out);
}

// Round 16
// 341.968 us; speedup vs baseline: 1.1497x; 1.1497x over previous
//
#include <hip/hip_runtime.h>
#include <hip/hip_bf16.h>

#define NTOK 2048   // B*S
#define HD   1024
#define FD   3584
#define NE   8

#define BM 128              // gemm1 m-tile
#define BN1 64              // gemm1 f-tile
#define BM2 64              // gemm2 m-tile
#define BN 128              // gemm2 h-tile
#define BK 64
#define NIT1 (HD / BK)      // 16
#define KS2 2               // gemm2 K-split
#define KLEN2 (FD / KS2)    // 1792
#define NIT2 (KLEN2 / BK)   // 28

typedef __attribute__((ext_vector_type(8))) short short8;
typedef __attribute__((ext_vector_type(4))) float f32x4;

__device__ __forceinline__ unsigned short f2bf(float f) {
    __hip_bfloat16 h = __float2bfloat16(f);
    union { __hip_bfloat16 h; unsigned short u; } c; c.h = h;
    return c.u;
}

// global_load_lds width=16
typedef __attribute__((address_space(1))) const unsigned int g_cu32;
typedef __attribute__((address_space(3))) unsigned int l_u32;
__device__ __forceinline__ void gl16(const void* g, void* l) {
    __builtin_amdgcn_global_load_lds((g_cu32*)g, (l_u32*)(unsigned int)(size_t)l, 16, 0, 0);
}

// ---------------- router ----------------
__global__ void k_router(const float* __restrict__ x, const float* __restrict__ gw,
                         int* __restrict__ sel, float* __restrict__ selw,
                         int* __restrict__ counts) {
    int token = blockIdx.x * 4 + (threadIdx.x >> 6);
    int lane  = threadIdx.x & 63;
    if (token >= NTOK) return;
    const float* xr = x + (size_t)token * HD;
    float acc[NE];
#pragma unroll
    for (int e = 0; e < NE; e++) acc[e] = 0.f;
    for (int h = lane; h < HD; h += 64) {
        float xv = xr[h];
        const float4* g = (const float4*)(gw + (size_t)h * NE);
        float4 g0 = g[0], g1 = g[1];
        acc[0] += xv * g0.x; acc[1] += xv * g0.y; acc[2] += xv * g0.z; acc[3] += xv * g0.w;
        acc[4] += xv * g1.x; acc[5] += xv * g1.y; acc[6] += xv * g1.z; acc[7] += xv * g1.w;
    }
#pragma unroll
    for (int e = 0; e < NE; e++) {
#pragma unroll
        for (int off = 32; off >= 1; off >>= 1) acc[e] += __shfl_xor(acc[e], off, 64);
    }
    if (lane == 0) {
        float m = acc[0];
#pragma unroll
        for (int e = 1; e < NE; e++) m = fmaxf(m, acc[e]);
        float z[NE];
#pragma unroll
        for (int e = 0; e < NE; e++) z[e] = expf(acc[e] - m);
        int e0 = 0; float z0 = z[0];
#pragma unroll
        for (int e = 1; e < NE; e++) if (z[e] > z0) { z0 = z[e]; e0 = e; }
        int e1 = -1; float z1 = -1.f;
#pragma unroll
        for (int e = 0; e < NE; e++) if (e != e0 && z[e] > z1) { z1 = z[e]; e1 = e; }
        float s = z0 + z1;
        sel[token * 2 + 0] = e0; sel[token * 2 + 1] = e1;
        selw[token * 2 + 0] = z0 / s; selw[token * 2 + 1] = z1 / s;
        atomicAdd(&counts[e0], 1);
        atomicAdd(&counts[e1], 1);
    }
}

__global__ void k_scan(const int* __restrict__ counts, int* __restrict__ basep,
                       int* __restrict__ fillc) {
    if (threadIdx.x == 0 && blockIdx.x == 0) {
        int b = 0;
        for (int e = 0; e < NE; e++) { basep[e] = b; b += counts[e]; fillc[e] = 0; }
    }
}

__global__ void k_fill(const int* __restrict__ sel, const float* __restrict__ selw,
                       const int* __restrict__ basep, int* __restrict__ fillc,
                       int* __restrict__ rowmap, int* __restrict__ rowk,
                       float* __restrict__ roww) {
    int n = blockIdx.x * blockDim.x + threadIdx.x;
    if (n >= NTOK) return;
#pragma unroll
    for (int k = 0; k < 2; k++) {
        int e = sel[n * 2 + k];
        int p = atomicAdd(&fillc[e], 1);
        int g = basep[e] + p;
        rowmap[g] = n; rowk[g] = k; roww[g] = selw[n * 2 + k];
    }
}

// ---------------- x -> bf16 ----------------
__global__ void k_cvt(const float* __restrict__ x, unsigned short* __restrict__ xb) {
    size_t i = ((size_t)blockIdx.x * blockDim.x + threadIdx.x) * 8;
    float4 a = *(const float4*)(x + i);
    float4 b = *(const float4*)(x + i + 4);
    unsigned short p[8] __attribute__((aligned(16))) =
        { f2bf(a.x), f2bf(a.y), f2bf(a.z), f2bf(a.w),
          f2bf(b.x), f2bf(b.y), f2bf(b.z), f2bf(b.w) };
    *(uint4*)(xb + i) = *(uint4*)p;
}

// pack 8 fp32 (k-order) -> uint4 of 8 bf16
__device__ __forceinline__ uint4 pack8(const float4* bv, int c) {
#define BF(r) ((unsigned int)f2bf(((const float*)&bv[r])[c]))
    uint4 u;
    u.x = BF(0) | (BF(1) << 16);
    u.y = BF(2) | (BF(3) << 16);
    u.z = BF(4) | (BF(5) << 16);
    u.w = BF(6) | (BF(7) << 16);
#undef BF
    return u;
}

// ---------------- GEMM1: direct fp32 w1/w3, b128 conflict-free staging ----------------
// B: 128 thr/matrix (half=t>>7): nq=t&15 (cols 4nq), kt=(t>>4)&7 (k-rows 8kt..+7).
// 8 float4 loads (256B runs along N) -> 4 ds_write_b128 at chunk kt^(n&7)
// (8 quads x 8 lanes per instr = uniform, same shape as the measured-0 reads).
// Two-ahead B pipeline: regs hold tile t+1 at iter-t top; write LDS(t+1), load
// regs(t+2); vmcnt(8) drains only A-gloads, keeps 8 B loads in flight.
__global__ __launch_bounds__(256, 2) void k_gemm1(
    const unsigned short* __restrict__ xb,
    const float* __restrict__ w1, const float* __restrict__ w3,
    const int* __restrict__ counts, const int* __restrict__ basep,
    const int* __restrict__ rowmap, unsigned short* __restrict__ act)
{
    const int e = blockIdx.z;
    const int nrows = counts[e];
    const int m0 = blockIdx.y * BM;
    if (m0 >= nrows) return;
    const int f0 = blockIdx.x * BN1;
    const int gbase = basep[e];

    __shared__ __align__(16) unsigned short At[2][BM][BK];
    __shared__ __align__(16) unsigned short B1[2][BN1][BK];
    __shared__ __align__(16) unsigned short B3[2][BN1][BK];

    const int t = threadIdx.x;
    const int lane = t & 63;
    const int w = t >> 6;                 // 0..3
    const int wrm = w >> 1, wnn = w & 1;  // 2x2 wave grid; wave tile 64 x 32
    const int lr = lane >> 3;
    const int so = ((lane & 7) ^ lr) * 8; // A staging pre-swizzle (verified)

    const unsigned short* asrc[4];
#pragma unroll
    for (int c = 0; c < 4; c++) {
        const int row = (w * 4 + c) * 8 + lr;
        const int tok = rowmap[gbase + min(m0 + row, nrows - 1)];
        asrc[c] = xb + (size_t)tok * HD + so;
    }

    // B staging mapping
    const int nq = t & 15;
    const int kt = (t >> 4) & 7;
    const int half = t >> 7;
    const float* bp = (half ? w3 : w1) + (size_t)e * HD * FD + (size_t)(8 * kt) * FD + f0 + 4 * nq;
    unsigned short* const bb = half ? &B3[0][0][0] : &B1[0][0][0];
    const int BUFS = BN1 * BK;            // ushorts per buffer

    f32x4 acc1[4][2], acc3[4][2];
#pragma unroll
    for (int i = 0; i < 4; i++)
#pragma unroll
        for (int j = 0; j < 2; j++) { acc1[i][j] = (f32x4)(0.f); acc3[i][j] = (f32x4)(0.f); }

    const int l15 = lane & 15;
    const int lhi = lane >> 4;
    const int rs = (l15 & 7) * 8;

    float4 bv[8];

#define G1_WRITE(buf_) do {                                                     \
    _Pragma("unroll")                                                           \
    for (int c = 0; c < 4; c++) {                                               \
        const int n = 4 * nq + c;                                               \
        *(uint4*)&bb[(buf_) * BUFS + n * BK + 8 * (kt ^ (n & 7))] = pack8(bv, c); \
    }                                                                           \
} while (0)

    // prologue: B(0) regs, A(0) gloads, write B(0), load B(1)
#pragma unroll
    for (int r = 0; r < 8; r++) bv[r] = *(const float4*)(bp + (size_t)r * FD);
#pragma unroll
    for (int c = 0; c < 4; c++) gl16(asrc[c], &At[0][(w * 4 + c) * 8][0]);
    G1_WRITE(0);
    if (NIT1 > 1) {
#pragma unroll
        for (int r = 0; r < 8; r++) bv[r] = *(const float4*)(bp + (size_t)(BK + r) * FD);
        asm volatile("s_waitcnt lgkmcnt(0)" ::: "memory");
        asm volatile("s_waitcnt vmcnt(8)" ::: "memory");   // drain A(0); B(1) in flight
    } else {
        asm volatile("s_waitcnt lgkmcnt(0)" ::: "memory");
        asm volatile("s_waitcnt vmcnt(0)" ::: "memory");
    }
    __builtin_amdgcn_s_barrier();

    for (int it = 0; it < NIT1; ++it) {
        const int cur = it & 1;
        const bool more = (it + 1 < NIT1);
        const bool more2 = (it + 2 < NIT1);
        if (more) {
#pragma unroll
            for (int c = 0; c < 4; c++)
                gl16(asrc[c] + (size_t)(it + 1) * BK, &At[cur ^ 1][(w * 4 + c) * 8][0]);
            G1_WRITE(cur ^ 1);                     // write tile t+1 (regs from last iter)
            if (more2) {
                const size_t k0 = (size_t)(it + 2) * BK;
#pragma unroll
                for (int r = 0; r < 8; r++) bv[r] = *(const float4*)(bp + (k0 + r) * FD);
            }
        }
#pragma unroll
        for (int kk = 0; kk < 2; kk++) {
            const int kc = (kk * 32 + lhi * 8) ^ rs;
            short8 af[4], b1f[2], b3f[2];
#pragma unroll
            for (int i = 0; i < 4; i++)
                af[i] = *(const short8*)&At[cur][wrm * 64 + i * 16 + l15][kc];
#pragma unroll
            for (int j = 0; j < 2; j++) {
                b1f[j] = *(const short8*)&B1[cur][wnn * 32 + j * 16 + l15][kc];
                b3f[j] = *(const short8*)&B3[cur][wnn * 32 + j * 16 + l15][kc];
            }
#pragma unroll
            for (int i = 0; i < 4; i++)
#pragma unroll
                for (int j = 0; j < 2; j++) {
                    acc1[i][j] = __builtin_amdgcn_mfma_f32_16x16x32_bf16(af[i], b1f[j], acc1[i][j], 0, 0, 0);
                    acc3[i][j] = __builtin_amdgcn_mfma_f32_16x16x32_bf16(af[i], b3f[j], acc3[i][j], 0, 0, 0);
                }
        }
        if (more) {
            asm volatile("s_waitcnt lgkmcnt(0)" ::: "memory");   // B(t+1) ds_writes done
            if (more2) asm volatile("s_waitcnt vmcnt(8)" ::: "memory");  // drain A(t+1), keep B(t+2)
            else       asm volatile("s_waitcnt vmcnt(0)" ::: "memory");
        }
        __builtin_amdgcn_s_barrier();
    }

    // epilogue: SwiGLU, bf16 act
    const int rbase = wrm * 64 + lhi * 4;
    const int cbase = f0 + wnn * 32 + l15;
#pragma unroll
    for (int i = 0; i < 4; i++) {
#pragma unroll
        for (int r = 0; r < 4; r++) {
            const int ml = rbase + i * 16 + r;
            if (m0 + ml < nrows) {
                const size_t rowoff = (size_t)(gbase + m0 + ml) * FD;
#pragma unroll
                for (int j = 0; j < 2; j++) {
                    float y1 = acc1[i][j][r];
                    float y3 = acc3[i][j][r];
                    float sv = (y1 / (1.f + __expf(-y1))) * y3;
                    act[rowoff + cbase + j * 16] = f2bf(sv);
                }
            }
        }
    }
#undef G1_WRITE
}

// ---------------- GEMM2: direct fp32 w2; BM2=64 x BN=128, K-split x2 ----------------
// B mapping: kt = ((l>>4)&3) | ((w&1)<<2), nq = (l&15) | ((w>>1)<<4)
// -> per wave: 16 consecutive nq (256B runs), 4 kt values -> 8 quads x 8 lanes.
__global__ __launch_bounds__(256, 3) void k_gemm2(
    const unsigned short* __restrict__ act,
    const float* __restrict__ w2,
    const int* __restrict__ counts, const int* __restrict__ basep,
    const int* __restrict__ rowmap, const int* __restrict__ rowk,
    const float* __restrict__ roww, float* __restrict__ partial)
{
    const int z = blockIdx.z;
    const int e = z >> 1, ks = z & 1;
    const int nrows = counts[e];
    const int m0 = blockIdx.y * BM2;
    if (m0 >= nrows) return;
    const int h0 = blockIdx.x * BN;
    const int gbase = basep[e];
    const int kbase = ks * KLEN2;

    __shared__ __align__(16) unsigned short At[2][BM2][BK];
    __shared__ __align__(16) unsigned short Bt[2][BN][BK];

    const int t = threadIdx.x;
    const int lane = t & 63;
    const int w = t >> 6;                 // 0..3
    const int wr2 = w >> 1, wn2 = w & 1;  // 2x2; wave tile 32 x 64
    const int lr = lane >> 3;
    const int so = ((lane & 7) ^ lr) * 8;

    const unsigned short* asrc[2];
#pragma unroll
    for (int c = 0; c < 2; c++) {
        const int row = (w * 2 + c) * 8 + lr;
        asrc[c] = act + ((size_t)gbase + min(m0 + row, nrows - 1)) * FD + so + kbase;
    }

    const int nq = (lane & 15) | ((w >> 1) << 4);   // 0..31
    const int kt = ((lane >> 4) & 3) | ((w & 1) << 2);  // 0..7
    const float* bp = w2 + (size_t)e * FD * HD + (size_t)(kbase + 8 * kt) * HD + h0 + 4 * nq;
    unsigned short* const bb = &Bt[0][0][0];
    const int BUFS2 = BN * BK;

    f32x4 acc[2][4];
#pragma unroll
    for (int i = 0; i < 2; i++)
#pragma unroll
        for (int j = 0; j < 4; j++) acc[i][j] = (f32x4)(0.f);

    const int l15 = lane & 15;
    const int lhi = lane >> 4;
    const int rs = (l15 & 7) * 8;

    float4 bv[8];

#define G2_WRITE(buf_) do {                                                     \
    _Pragma("unroll")                                                           \
    for (int c = 0; c < 4; c++) {                                               \
        const int n = 4 * nq + c;                                               \
        *(uint4*)&bb[(buf_) * BUFS2 + n * BK + 8 * (kt ^ (n & 7))] = pack8(bv, c); \
    }                                                                           \
} while (0)

    // prologue
#pragma unroll
    for (int r = 0; r < 8; r++) bv[r] = *(const float4*)(bp + (size_t)r * HD);
#pragma unroll
    for (int c = 0; c < 2; c++) gl16(asrc[c], &At[0][(w * 2 + c) * 8][0]);
    G2_WRITE(0);
    if (NIT2 > 1) {
#pragma unroll
        for (int r = 0; r < 8; r++) bv[r] = *(const float4*)(bp + (size_t)(BK + r) * HD);
        asm volatile("s_waitcnt lgkmcnt(0)" ::: "memory");
        asm volatile("s_waitcnt vmcnt(8)" ::: "memory");
    } else {
        asm volatile("s_waitcnt lgkmcnt(0)" ::: "memory");
        asm volatile("s_waitcnt vmcnt(0)" ::: "memory");
    }
    __builtin_amdgcn_s_barrier();

    for (int it = 0; it < NIT2; ++it) {
        const int cur = it & 1;
        const bool more = (it + 1 < NIT2);
        const bool more2 = (it + 2 < NIT2);
        if (more) {
#pragma unroll
            for (int c = 0; c < 2; c++)
                gl16(asrc[c] + (size_t)(it + 1) * BK, &At[cur ^ 1][(w * 2 + c) * 8][0]);
            G2_WRITE(cur ^ 1);
            if (more2) {
                const size_t k0 = (size_t)(it + 2) * BK;
#pragma unroll
                for (int r = 0; r < 8; r++) bv[r] = *(const float4*)(bp + (k0 + r) * HD);
            }
        }
#pragma unroll
        for (int kk = 0; kk < 2; kk++) {
            const int kc = (kk * 32 + lhi * 8) ^ rs;
            short8 af[2], bf[4];
#pragma unroll
            for (int i = 0; i < 2; i++)
                af[i] = *(const short8*)&At[cur][wr2 * 32 + i * 16 + l15][kc];
#pragma unroll
            for (int j = 0; j < 4; j++)
                bf[j] = *(const short8*)&Bt[cur][wn2 * 64 + j * 16 + l15][kc];
#pragma unroll
            for (int i = 0; i < 2; i++)
#pragma unroll
                for (int j = 0; j < 4; j++)
                    acc[i][j] = __builtin_amdgcn_mfma_f32_16x16x32_bf16(af[i], bf[j], acc[i][j], 0, 0, 0);
        }
        if (more) {
            asm volatile("s_waitcnt lgkmcnt(0)" ::: "memory");
            if (more2) asm volatile("s_waitcnt vmcnt(8)" ::: "memory");
            else       asm volatile("s_waitcnt vmcnt(0)" ::: "memory");
        }
        __builtin_amdgcn_s_barrier();
    }

    const int rbase = wr2 * 32 + lhi * 4;
    const int cbase = h0 + wn2 * 64 + l15;
#pragma unroll
    for (int i = 0; i < 2; i++) {
#pragma unroll
        for (int r = 0; r < 4; r++) {
            const int ml = rbase + i * 16 + r;
            if (m0 + ml < nrows) {
                const int grow = gbase + m0 + ml;
                const int tok = rowmap[grow];
                const int slot = rowk[grow];
                const float wv = roww[grow];
                float* op = partial + (((size_t)slot * KS2 + ks) * NTOK + tok) * HD + cbase;
#pragma unroll
                for (int j = 0; j < 4; j++) op[j * 16] = acc[i][j][r] * wv;
            }
        }
    }
#undef G2_WRITE
}

__global__ void k_combine(const float* __restrict__ partial, float* __restrict__ out) {
    size_t i = ((size_t)blockIdx.x * blockDim.x + threadIdx.x) * 4;
    const size_t st = (size_t)NTOK * HD;
    float4 o = *(const float4*)(partial + i);
#pragma unroll
    for (int s = 1; s < 2 * KS2; s++) {
        float4 v = *(const float4*)(partial + (size_t)s * st + i);
        o.x += v.x; o.y += v.y; o.z += v.z; o.w += v.w;
    }
    *(float4*)(out + i) = o;
}

extern "C" void kernel_launch(void* const* d_in, const int* in_sizes, int n_in,
                              void* d_out, int out_size, void* d_ws, size_t ws_size,
                              hipStream_t stream) {
    const float* x  = (const float*)d_in[0];
    const float* gw = (const float*)d_in[1];
    const float* w1 = (const float*)d_in[2];
    const float* w3 = (const float*)d_in[3];
    const float* w2 = (const float*)d_in[4];
    float* out = (float*)d_out;

    char* ws = (char*)d_ws;
    size_t off = 0;
    auto alloc = [&](size_t b) { char* p = ws + off; off += (b + 255) & ~(size_t)255; return p; };
    int*   sel    = (int*)  alloc((size_t)NTOK * 2 * 4);
    float* selw   = (float*)alloc((size_t)NTOK * 2 * 4);
    int*   counts = (int*)  alloc(NE * 4);
    int*   basep  = (int*)  alloc(NE * 4);
    int*   fillc  = (int*)  alloc(NE * 4);
    int*   rowmap = (int*)  alloc((size_t)NTOK * 2 * 4);
    int*   rowk   = (int*)  alloc((size_t)NTOK * 2 * 4);
    float* roww   = (float*)alloc((size_t)NTOK * 2 * 4);
    unsigned short* xb  = (unsigned short*)alloc((size_t)NTOK * HD * 2);
    unsigned short* act = (unsigned short*)alloc((size_t)NTOK * 2 * FD * 2);
    float* partial = (float*)alloc((size_t)2 * KS2 * NTOK * HD * 4);

    hipMemsetAsync(counts, 0, NE * 4, stream);
    k_cvt<<<(NTOK * HD) / (256 * 8), 256, 0, stream>>>(x, xb);
    k_router<<<NTOK / 4, 256, 0, stream>>>(x, gw, sel, selw, counts);
    k_scan<<<1, 64, 0, stream>>>(counts, basep, fillc);
    k_fill<<<NTOK / 256, 256, 0, stream>>>(sel, selw, basep, fillc, rowmap, rowk, roww);
    k_gemm1<<<dim3(FD / BN1, NTOK / BM, NE), 256, 0, stream>>>(xb, w1, w3, counts, basep, rowmap, act);
    k_gemm2<<<dim3(HD / BN, NTOK / BM2, NE * KS2), 256, 0, stream>>>(act, w2, counts, basep, rowmap, rowk, roww, partial);
    k_combine<<<(NTOK * HD) / (256 * 4), 256, 0, stream>>>(partial, out);
}

// Round 17
// 330.547 us; speedup vs baseline: 1.1895x; 1.0346x over previous
//
#include <hip/hip_runtime.h>
#include <hip/hip_bf16.h>

#define NTOK 2048   // B*S
#define HD   1024
#define FD   3584
#define NE   8

#define BM 128              // gemm1 m-tile
#define BN1 64              // gemm1 f-tile
#define BM2 64              // gemm2 m-tile
#define BN 128              // gemm2 h-tile
#define BK 64               // 128B LDS rows (verified conflict-free layout)
#define NIT1 (HD / BK)      // 16
#define KS2 2               // gemm2 K-split
#define KLEN2 (FD / KS2)    // 1792
#define NIT2 (KLEN2 / BK)   // 28

typedef __attribute__((ext_vector_type(8))) short short8;
typedef __attribute__((ext_vector_type(4))) float f32x4;

__device__ __forceinline__ unsigned short f2bf(float f) {
    __hip_bfloat16 h = __float2bfloat16(f);
    union { __hip_bfloat16 h; unsigned short u; } c; c.h = h;
    return c.u;
}

// global_load_lds width=16: per-lane 16B global src -> wave-uniform LDS base + lane*16
typedef __attribute__((address_space(1))) const unsigned int g_cu32;
typedef __attribute__((address_space(3))) unsigned int l_u32;
__device__ __forceinline__ void gl16(const void* g, void* l) {
    __builtin_amdgcn_global_load_lds((g_cu32*)g, (l_u32*)(unsigned int)(size_t)l, 16, 0, 0);
}

// ---------------- router: fp32 logits, softmax, top-2, renorm ----------------
__global__ void k_router(const float* __restrict__ x, const float* __restrict__ gw,
                         int* __restrict__ sel, float* __restrict__ selw,
                         int* __restrict__ counts) {
    int token = blockIdx.x * 4 + (threadIdx.x >> 6);
    int lane  = threadIdx.x & 63;
    if (token >= NTOK) return;
    const float* xr = x + (size_t)token * HD;
    float acc[NE];
#pragma unroll
    for (int e = 0; e < NE; e++) acc[e] = 0.f;
    for (int h = lane; h < HD; h += 64) {
        float xv = xr[h];
        const float4* g = (const float4*)(gw + (size_t)h * NE);
        float4 g0 = g[0], g1 = g[1];
        acc[0] += xv * g0.x; acc[1] += xv * g0.y; acc[2] += xv * g0.z; acc[3] += xv * g0.w;
        acc[4] += xv * g1.x; acc[5] += xv * g1.y; acc[6] += xv * g1.z; acc[7] += xv * g1.w;
    }
#pragma unroll
    for (int e = 0; e < NE; e++) {
#pragma unroll
        for (int off = 32; off >= 1; off >>= 1) acc[e] += __shfl_xor(acc[e], off, 64);
    }
    if (lane == 0) {
        float m = acc[0];
#pragma unroll
        for (int e = 1; e < NE; e++) m = fmaxf(m, acc[e]);
        float z[NE];
#pragma unroll
        for (int e = 0; e < NE; e++) z[e] = expf(acc[e] - m);
        int e0 = 0; float z0 = z[0];
#pragma unroll
        for (int e = 1; e < NE; e++) if (z[e] > z0) { z0 = z[e]; e0 = e; }
        int e1 = -1; float z1 = -1.f;
#pragma unroll
        for (int e = 0; e < NE; e++) if (e != e0 && z[e] > z1) { z1 = z[e]; e1 = e; }
        float s = z0 + z1;
        sel[token * 2 + 0] = e0; sel[token * 2 + 1] = e1;
        selw[token * 2 + 0] = z0 / s; selw[token * 2 + 1] = z1 / s;
        atomicAdd(&counts[e0], 1);
        atomicAdd(&counts[e1], 1);
    }
}

__global__ void k_scan(const int* __restrict__ counts, int* __restrict__ basep,
                       int* __restrict__ fillc) {
    if (threadIdx.x == 0 && blockIdx.x == 0) {
        int b = 0;
        for (int e = 0; e < NE; e++) { basep[e] = b; b += counts[e]; fillc[e] = 0; }
    }
}

__global__ void k_fill(const int* __restrict__ sel, const float* __restrict__ selw,
                       const int* __restrict__ basep, int* __restrict__ fillc,
                       int* __restrict__ rowmap, int* __restrict__ rowk,
                       float* __restrict__ roww) {
    int n = blockIdx.x * blockDim.x + threadIdx.x;
    if (n >= NTOK) return;
#pragma unroll
    for (int k = 0; k < 2; k++) {
        int e = sel[n * 2 + k];
        int p = atomicAdd(&fillc[e], 1);
        int g = basep[e] + p;
        rowmap[g] = n; rowk[g] = k; roww[g] = selw[n * 2 + k];
    }
}

// ---------------- x -> bf16 ----------------
__global__ void k_cvt(const float* __restrict__ x, unsigned short* __restrict__ xb) {
    size_t i = ((size_t)blockIdx.x * blockDim.x + threadIdx.x) * 8;
    float4 a = *(const float4*)(x + i);
    float4 b = *(const float4*)(x + i + 4);
    unsigned short p[8] __attribute__((aligned(16))) =
        { f2bf(a.x), f2bf(a.y), f2bf(a.z), f2bf(a.w),
          f2bf(b.x), f2bf(b.y), f2bf(b.z), f2bf(b.w) };
    *(uint4*)(xb + i) = *(uint4*)p;
}

// ---------------- fused weight transpose+convert, pair-packed vector LDS (r11) ----------------
__global__ void k_wt3(const float* __restrict__ w1, const float* __restrict__ w3,
                      const float* __restrict__ w2,
                      unsigned short* __restrict__ w1t, unsigned short* __restrict__ w3t,
                      unsigned short* __restrict__ w2t) {
    __shared__ unsigned int P[64 * 32];   // 8 KB pair layout: [n][32 k-pairs]
    const int z = blockIdx.z;
    int K, N, tx, ty;
    const float* src;
    unsigned short* dst;
    if (z < 16) {
        K = HD; N = FD;
        const int e = z & 7;
        src = (z < 8 ? w1 : w3) + (size_t)e * K * N;
        dst = (z < 8 ? w1t : w3t) + (size_t)e * N * K;
        tx = blockIdx.x % (FD / 64); ty = blockIdx.x / (FD / 64);
    } else {
        K = FD; N = HD;
        const int e = z - 16;
        src = w2 + (size_t)e * K * N;
        dst = w2t + (size_t)e * N * K;
        tx = blockIdx.x % (HD / 64); ty = blockIdx.x / (HD / 64);
    }
    src += (size_t)(ty * 64) * N + tx * 64;
    dst += (size_t)(tx * 64) * K + ty * 64;

    const int t = threadIdx.x;
    {
        const int rp = t >> 3;            // k-pair index 0..31
        const int c8 = t & 7;             // 8-col group
        const float* s0 = src + (size_t)(2 * rp) * N + c8 * 8;
        const float* s1 = s0 + N;
        float4 a0 = *(const float4*)(s0);
        float4 a1 = *(const float4*)(s0 + 4);
        float4 b0 = *(const float4*)(s1);
        float4 b1 = *(const float4*)(s1 + 4);
        float ev[8] = { a0.x, a0.y, a0.z, a0.w, a1.x, a1.y, a1.z, a1.w };
        float od[8] = { b0.x, b0.y, b0.z, b0.w, b1.x, b1.y, b1.z, b1.w };
#pragma unroll
        for (int j = 0; j < 8; j++) {
            const int n = c8 * 8 + j;
            unsigned int v = (unsigned int)f2bf(ev[j]) | ((unsigned int)f2bf(od[j]) << 16);
            P[n * 32 + (rp ^ ((n >> 3) << 2))] = v;
        }
    }
    __syncthreads();
    {
        const int n = t >> 2;             // output row (source col) 0..63
#pragma unroll
        for (int it = 0; it < 2; it++) {
            const int q = (t & 3) + 4 * it;   // k-octet 0..7
            uint4 v = *(const uint4*)&P[n * 32 + 4 * (q ^ (n >> 3))];
            *(uint4*)&dst[(size_t)n * K + q * 8] = v;
        }
    }
}

// ---------------- GEMM1: 256 thr, 4 waves 2x2, wave tile 64x32 (r11) ----------------
__global__ __launch_bounds__(256, 2) void k_gemm1(
    const unsigned short* __restrict__ xb,
    const unsigned short* __restrict__ w1t, const unsigned short* __restrict__ w3t,
    const int* __restrict__ counts, const int* __restrict__ basep,
    const int* __restrict__ rowmap, unsigned short* __restrict__ act)
{
    const int e = blockIdx.z;
    const int nrows = counts[e];
    const int m0 = blockIdx.y * BM;
    if (m0 >= nrows) return;
    const int f0 = blockIdx.x * BN1;
    const int gbase = basep[e];

    __shared__ __align__(16) unsigned short At[2][BM][BK];
    __shared__ __align__(16) unsigned short B1[2][BN1][BK];
    __shared__ __align__(16) unsigned short B3[2][BN1][BK];

    const int t = threadIdx.x;
    const int lane = t & 63;
    const int w = t >> 6;                 // 0..3
    const int wrm = w >> 1, wnn = w & 1;  // 2x2 wave grid; wave tile 64 x 32
    const int lr = lane >> 3;
    const int so = ((lane & 7) ^ lr) * 8; // verified swizzle: chunk ^ (row&7)

    const unsigned short* asrc[4];
#pragma unroll
    for (int c = 0; c < 4; c++) {
        const int row = (w * 4 + c) * 8 + lr;
        const int tok = rowmap[gbase + min(m0 + row, nrows - 1)];
        asrc[c] = xb + (size_t)tok * HD + so;
    }
    const unsigned short* b1src[2];
    const unsigned short* b3src[2];
#pragma unroll
    for (int c = 0; c < 2; c++) {
        const int row = (w * 2 + c) * 8 + lr;
        b1src[c] = w1t + ((size_t)(e * FD + f0 + row)) * HD + so;
        b3src[c] = w3t + ((size_t)(e * FD + f0 + row)) * HD + so;
    }

    f32x4 acc1[4][2], acc3[4][2];
#pragma unroll
    for (int i = 0; i < 4; i++)
#pragma unroll
        for (int j = 0; j < 2; j++) { acc1[i][j] = (f32x4)(0.f); acc3[i][j] = (f32x4)(0.f); }

    const int l15 = lane & 15;
    const int lhi = lane >> 4;
    const int rs = (l15 & 7) * 8;

    // prologue: stage k-tile 0 into buf 0 (8 loads/thread in flight)
#pragma unroll
    for (int c = 0; c < 4; c++) gl16(asrc[c], &At[0][(w * 4 + c) * 8][0]);
#pragma unroll
    for (int c = 0; c < 2; c++) {
        gl16(b1src[c], &B1[0][(w * 2 + c) * 8][0]);
        gl16(b3src[c], &B3[0][(w * 2 + c) * 8][0]);
    }

    for (int it = 0; it < NIT1; ++it) {
        const int cur = it & 1;
        if (it + 1 < NIT1) {
            const int kn = (it + 1) * BK;
#pragma unroll
            for (int c = 0; c < 4; c++) gl16(asrc[c] + kn, &At[cur ^ 1][(w * 4 + c) * 8][0]);
#pragma unroll
            for (int c = 0; c < 2; c++) {
                gl16(b1src[c] + kn, &B1[cur ^ 1][(w * 2 + c) * 8][0]);
                gl16(b3src[c] + kn, &B3[cur ^ 1][(w * 2 + c) * 8][0]);
            }
            asm volatile("s_waitcnt vmcnt(8)" ::: "memory");   // wait current tile only
        } else {
            asm volatile("s_waitcnt vmcnt(0)" ::: "memory");
        }
        __builtin_amdgcn_s_barrier();
#pragma unroll
        for (int kk = 0; kk < 2; kk++) {
            const int kc = (kk * 32 + lhi * 8) ^ rs;
            short8 af[4], b1f[2], b3f[2];
#pragma unroll
            for (int i = 0; i < 4; i++)
                af[i] = *(const short8*)&At[cur][wrm * 64 + i * 16 + l15][kc];
#pragma unroll
            for (int j = 0; j < 2; j++) {
                b1f[j] = *(const short8*)&B1[cur][wnn * 32 + j * 16 + l15][kc];
                b3f[j] = *(const short8*)&B3[cur][wnn * 32 + j * 16 + l15][kc];
            }
#pragma unroll
            for (int i = 0; i < 4; i++)
#pragma unroll
                for (int j = 0; j < 2; j++) {
                    acc1[i][j] = __builtin_amdgcn_mfma_f32_16x16x32_bf16(af[i], b1f[j], acc1[i][j], 0, 0, 0);
                    acc3[i][j] = __builtin_amdgcn_mfma_f32_16x16x32_bf16(af[i], b3f[j], acc3[i][j], 0, 0, 0);
                }
        }
        __builtin_amdgcn_s_barrier();
    }

    // epilogue: SwiGLU, bf16 act
    const int rbase = wrm * 64 + lhi * 4;
    const int cbase = f0 + wnn * 32 + l15;
#pragma unroll
    for (int i = 0; i < 4; i++) {
#pragma unroll
        for (int r = 0; r < 4; r++) {
            const int ml = rbase + i * 16 + r;
            if (m0 + ml < nrows) {
                const size_t rowoff = (size_t)(gbase + m0 + ml) * FD;
#pragma unroll
                for (int j = 0; j < 2; j++) {
                    float y1 = acc1[i][j][r];
                    float y3 = acc3[i][j][r];
                    float sv = (y1 / (1.f + __expf(-y1))) * y3;
                    act[rowoff + cbase + j * 16] = f2bf(sv);
                }
            }
        }
    }
}

// ---------------- GEMM2: BM2=64 x BN=128, wave tile 32x64, K-split x2 (r11) ----------------
// r17: epilogue atomically accumulates into out (partial/combine eliminated).
__global__ __launch_bounds__(256, 4) void k_gemm2(
    const unsigned short* __restrict__ act,
    const unsigned short* __restrict__ w2t,
    const int* __restrict__ counts, const int* __restrict__ basep,
    const int* __restrict__ rowmap, const int* __restrict__ rowk,
    const float* __restrict__ roww, float* __restrict__ out)
{
    const int z = blockIdx.z;
    const int e = z >> 1, ks = z & 1;
    const int nrows = counts[e];
    const int m0 = blockIdx.y * BM2;
    if (m0 >= nrows) return;
    const int h0 = blockIdx.x * BN;
    const int gbase = basep[e];
    const int kbase = ks * KLEN2;

    __shared__ __align__(16) unsigned short At[2][BM2][BK];
    __shared__ __align__(16) unsigned short Bt[2][BN][BK];

    const int t = threadIdx.x;
    const int lane = t & 63;
    const int w = t >> 6;                 // 0..3
    const int wr2 = w >> 1, wn2 = w & 1;  // 2x2; wave tile 32 x 64
    const int lr = lane >> 3;
    const int so = ((lane & 7) ^ lr) * 8;

    const unsigned short* asrc[2];
#pragma unroll
    for (int c = 0; c < 2; c++) {
        const int row = (w * 2 + c) * 8 + lr;
        asrc[c] = act + ((size_t)gbase + min(m0 + row, nrows - 1)) * FD + so + kbase;
    }
    const unsigned short* bsrc[4];
#pragma unroll
    for (int c = 0; c < 4; c++) {
        const int row = (w * 4 + c) * 8 + lr;
        bsrc[c] = w2t + ((size_t)(e * HD + h0 + row)) * FD + so + kbase;
    }

    f32x4 acc[2][4];
#pragma unroll
    for (int i = 0; i < 2; i++)
#pragma unroll
        for (int j = 0; j < 4; j++) acc[i][j] = (f32x4)(0.f);

    const int l15 = lane & 15;
    const int lhi = lane >> 4;
    const int rs = (l15 & 7) * 8;

    // prologue: stage tile 0 into buf 0 (6 loads/thread)
#pragma unroll
    for (int c = 0; c < 2; c++) gl16(asrc[c], &At[0][(w * 2 + c) * 8][0]);
#pragma unroll
    for (int c = 0; c < 4; c++) gl16(bsrc[c], &Bt[0][(w * 4 + c) * 8][0]);

    for (int it = 0; it < NIT2; ++it) {
        const int cur = it & 1;
        if (it + 1 < NIT2) {
            const int kn = (it + 1) * BK;
#pragma unroll
            for (int c = 0; c < 2; c++) gl16(asrc[c] + kn, &At[cur ^ 1][(w * 2 + c) * 8][0]);
#pragma unroll
            for (int c = 0; c < 4; c++) gl16(bsrc[c] + kn, &Bt[cur ^ 1][(w * 4 + c) * 8][0]);
            asm volatile("s_waitcnt vmcnt(6)" ::: "memory");
        } else {
            asm volatile("s_waitcnt vmcnt(0)" ::: "memory");
        }
        __builtin_amdgcn_s_barrier();
#pragma unroll
        for (int kk = 0; kk < 2; kk++) {
            const int kc = (kk * 32 + lhi * 8) ^ rs;
            short8 af[2], bf[4];
#pragma unroll
            for (int i = 0; i < 2; i++)
                af[i] = *(const short8*)&At[cur][wr2 * 32 + i * 16 + l15][kc];
#pragma unroll
            for (int j = 0; j < 4; j++)
                bf[j] = *(const short8*)&Bt[cur][wn2 * 64 + j * 16 + l15][kc];
#pragma unroll
            for (int i = 0; i < 2; i++)
#pragma unroll
                for (int j = 0; j < 4; j++)
                    acc[i][j] = __builtin_amdgcn_mfma_f32_16x16x32_bf16(af[i], bf[j], acc[i][j], 0, 0, 0);
        }
        __builtin_amdgcn_s_barrier();
    }

    const int rbase = wr2 * 32 + lhi * 4;
    const int cbase = h0 + wn2 * 64 + l15;
#pragma unroll
    for (int i = 0; i < 2; i++) {
#pragma unroll
        for (int r = 0; r < 4; r++) {
            const int ml = rbase + i * 16 + r;
            if (m0 + ml < nrows) {
                const int grow = gbase + m0 + ml;
                const int tok = rowmap[grow];
                const float wv = roww[grow];
                float* op = out + (size_t)tok * HD + cbase;
#pragma unroll
                for (int j = 0; j < 4; j++)
                    atomicAdd(&op[j * 16], acc[i][j][r] * wv);
            }
        }
    }
}

extern "C" void kernel_launch(void* const* d_in, const int* in_sizes, int n_in,
                              void* d_out, int out_size, void* d_ws, size_t ws_size,
                              hipStream_t stream) {
    const float* x  = (const float*)d_in[0];
    const float* gw = (const float*)d_in[1];
    const float* w1 = (const float*)d_in[2];
    const float* w3 = (const float*)d_in[3];
    const float* w2 = (const float*)d_in[4];
    float* out = (float*)d_out;

    char* ws = (char*)d_ws;
    size_t off = 0;
    auto alloc = [&](size_t b) { char* p = ws + off; off += (b + 255) & ~(size_t)255; return p; };
    int*   sel    = (int*)  alloc((size_t)NTOK * 2 * 4);
    float* selw   = (float*)alloc((size_t)NTOK * 2 * 4);
    int*   counts = (int*)  alloc(NE * 4);
    int*   basep  = (int*)  alloc(NE * 4);
    int*   fillc  = (int*)  alloc(NE * 4);
    int*   rowmap = (int*)  alloc((size_t)NTOK * 2 * 4);
    int*   rowk   = (int*)  alloc((size_t)NTOK * 2 * 4);
    float* roww   = (float*)alloc((size_t)NTOK * 2 * 4);
    unsigned short* xb  = (unsigned short*)alloc((size_t)NTOK * HD * 2);
    unsigned short* act = (unsigned short*)alloc((size_t)NTOK * 2 * FD * 2);
    unsigned short* w1t = (unsigned short*)alloc((size_t)NE * HD * FD * 2);
    unsigned short* w3t = (unsigned short*)alloc((size_t)NE * HD * FD * 2);
    unsigned short* w2t = (unsigned short*)alloc((size_t)NE * HD * FD * 2);

    hipMemsetAsync(counts, 0, NE * 4, stream);
    hipMemsetAsync(out, 0, (size_t)out_size * 4, stream);   // gemm2 accumulates atomically
    k_wt3<<<dim3(896, 1, 24), 256, 0, stream>>>(w1, w3, w2, w1t, w3t, w2t);
    k_cvt<<<(NTOK * HD) / (256 * 8), 256, 0, stream>>>(x, xb);
    k_router<<<NTOK / 4, 256, 0, stream>>>(x, gw, sel, selw, counts);
    k_scan<<<1, 64, 0, stream>>>(counts, basep, fillc);
    k_fill<<<NTOK / 256, 256, 0, stream>>>(sel, selw, basep, fillc, rowmap, rowk, roww);
    k_gemm1<<<dim3(FD / BN1, NTOK / BM, NE), 256, 0, stream>>>(xb, w1t, w3t, counts, basep, rowmap, act);
    k_gemm2<<<dim3(HD / BN, NTOK / BM2, NE * KS2), 256, 0, stream>>>(act, w2t, counts, basep, rowmap, rowk, roww, out);
}

// Round 18
// 329.604 us; speedup vs baseline: 1.1929x; 1.0029x over previous
//
#include <hip/hip_runtime.h>
#include <hip/hip_bf16.h>

#define NTOK 2048   // B*S
#define HD   1024
#define FD   3584
#define NE   8

#define BM 128              // gemm1 m-tile
#define BN1 64              // gemm1 f-tile
#define BM2 64              // gemm2 m-tile
#define BN 128              // gemm2 h-tile
#define BK 64               // 128B LDS rows (verified conflict-free layout)
#define NIT1 (HD / BK)      // 16
#define KS2 2               // gemm2 K-split
#define KLEN2 (FD / KS2)    // 1792
#define NIT2 (KLEN2 / BK)   // 28
#define TSZ 4096            // shorts per 64x64 weight tile (8KB)

typedef __attribute__((ext_vector_type(8))) short short8;
typedef __attribute__((ext_vector_type(4))) float f32x4;

__device__ __forceinline__ unsigned short f2bf(float f) {
    __hip_bfloat16 h = __float2bfloat16(f);
    union { __hip_bfloat16 h; unsigned short u; } c; c.h = h;
    return c.u;
}

// global_load_lds width=16: per-lane 16B global src -> wave-uniform LDS base + lane*16
typedef __attribute__((address_space(1))) const unsigned int g_cu32;
typedef __attribute__((address_space(3))) unsigned int l_u32;
__device__ __forceinline__ void gl16(const void* g, void* l) {
    __builtin_amdgcn_global_load_lds((g_cu32*)g, (l_u32*)(unsigned int)(size_t)l, 16, 0, 0);
}

// ---------------- router: fp32 logits, softmax, top-2, renorm ----------------
__global__ void k_router(const float* __restrict__ x, const float* __restrict__ gw,
                         int* __restrict__ sel, float* __restrict__ selw,
                         int* __restrict__ counts) {
    int token = blockIdx.x * 4 + (threadIdx.x >> 6);
    int lane  = threadIdx.x & 63;
    if (token >= NTOK) return;
    const float* xr = x + (size_t)token * HD;
    float acc[NE];
#pragma unroll
    for (int e = 0; e < NE; e++) acc[e] = 0.f;
    for (int h = lane; h < HD; h += 64) {
        float xv = xr[h];
        const float4* g = (const float4*)(gw + (size_t)h * NE);
        float4 g0 = g[0], g1 = g[1];
        acc[0] += xv * g0.x; acc[1] += xv * g0.y; acc[2] += xv * g0.z; acc[3] += xv * g0.w;
        acc[4] += xv * g1.x; acc[5] += xv * g1.y; acc[6] += xv * g1.z; acc[7] += xv * g1.w;
    }
#pragma unroll
    for (int e = 0; e < NE; e++) {
#pragma unroll
        for (int off = 32; off >= 1; off >>= 1) acc[e] += __shfl_xor(acc[e], off, 64);
    }
    if (lane == 0) {
        float m = acc[0];
#pragma unroll
        for (int e = 1; e < NE; e++) m = fmaxf(m, acc[e]);
        float z[NE];
#pragma unroll
        for (int e = 0; e < NE; e++) z[e] = expf(acc[e] - m);
        int e0 = 0; float z0 = z[0];
#pragma unroll
        for (int e = 1; e < NE; e++) if (z[e] > z0) { z0 = z[e]; e0 = e; }
        int e1 = -1; float z1 = -1.f;
#pragma unroll
        for (int e = 0; e < NE; e++) if (e != e0 && z[e] > z1) { z1 = z[e]; e1 = e; }
        float s = z0 + z1;
        sel[token * 2 + 0] = e0; sel[token * 2 + 1] = e1;
        selw[token * 2 + 0] = z0 / s; selw[token * 2 + 1] = z1 / s;
        atomicAdd(&counts[e0], 1);
        atomicAdd(&counts[e1], 1);
    }
}

__global__ void k_scan(const int* __restrict__ counts, int* __restrict__ basep,
                       int* __restrict__ fillc) {
    if (threadIdx.x == 0 && blockIdx.x == 0) {
        int b = 0;
        for (int e = 0; e < NE; e++) { basep[e] = b; b += counts[e]; fillc[e] = 0; }
    }
}

__global__ void k_fill(const int* __restrict__ sel, const float* __restrict__ selw,
                       const int* __restrict__ basep, int* __restrict__ fillc,
                       int* __restrict__ rowmap, int* __restrict__ rowk,
                       float* __restrict__ roww) {
    int n = blockIdx.x * blockDim.x + threadIdx.x;
    if (n >= NTOK) return;
#pragma unroll
    for (int k = 0; k < 2; k++) {
        int e = sel[n * 2 + k];
        int p = atomicAdd(&fillc[e], 1);
        int g = basep[e] + p;
        rowmap[g] = n; rowk[g] = k; roww[g] = selw[n * 2 + k];
    }
}

// ---------------- x -> bf16 ----------------
__global__ void k_cvt(const float* __restrict__ x, unsigned short* __restrict__ xb) {
    size_t i = ((size_t)blockIdx.x * blockDim.x + threadIdx.x) * 8;
    float4 a = *(const float4*)(x + i);
    float4 b = *(const float4*)(x + i + 4);
    unsigned short p[8] __attribute__((aligned(16))) =
        { f2bf(a.x), f2bf(a.y), f2bf(a.z), f2bf(a.w),
          f2bf(b.x), f2bf(b.y), f2bf(b.z), f2bf(b.w) };
    *(uint4*)(xb + i) = *(uint4*)p;
}

// ---------------- weight transpose+convert -> TILE-CONTIGUOUS layout (r18) ----------------
// Output layout: per expert, 64x64 tiles of 4096 shorts, [n-tile-major][k-tile-minor]:
//   w1t/w3t: tile_id = ftile*16 + ktile   (ftile 0..55, ktile 0..15)
//   w2t    : tile_id = ntile*56 + ktile   (ntile 0..15, ktile 0..55)
// Within a tile: [n64][k64] row-major (same as before within-tile).
// Phase-B writes are now FULLY SEQUENTIAL: thread t stores 16B at tile offset
// t*16B per pass (2 passes = 8KB tile) -- no more 2KB-stride 128B runs (the
// r11/r13/r14 null-result suspect). GEMMs read each tile as one contiguous
// 8KB block (gl16's per-lane global address makes layout a free variable).
__global__ void k_wt3(const float* __restrict__ w1, const float* __restrict__ w3,
                      const float* __restrict__ w2,
                      unsigned short* __restrict__ w1t, unsigned short* __restrict__ w3t,
                      unsigned short* __restrict__ w2t) {
    __shared__ unsigned int P[64 * 32];   // 8 KB pair layout: [n][32 k-pairs]
    const int z = blockIdx.z;
    int N, tx, ty;
    const float* src;
    unsigned short* dst;
    if (z < 16) {
        N = FD;
        const int e = z & 7;
        tx = blockIdx.x % (FD / 64); ty = blockIdx.x / (FD / 64);   // ftile, ktile
        src = (z < 8 ? w1 : w3) + (size_t)e * HD * FD;
        dst = (z < 8 ? w1t : w3t) + (size_t)e * HD * FD + ((size_t)tx * 16 + ty) * TSZ;
    } else {
        N = HD;
        const int e = z - 16;
        tx = blockIdx.x % (HD / 64); ty = blockIdx.x / (HD / 64);   // ntile, ktile
        src = w2 + (size_t)e * FD * HD;
        dst = w2t + (size_t)e * HD * FD + ((size_t)tx * 56 + ty) * TSZ;
    }
    src += (size_t)(ty * 64) * N + tx * 64;

    const int t = threadIdx.x;
    {
        const int rp = t >> 3;            // k-pair index 0..31
        const int c8 = t & 7;             // 8-col group
        const float* s0 = src + (size_t)(2 * rp) * N + c8 * 8;
        const float* s1 = s0 + N;
        float4 a0 = *(const float4*)(s0);
        float4 a1 = *(const float4*)(s0 + 4);
        float4 b0 = *(const float4*)(s1);
        float4 b1 = *(const float4*)(s1 + 4);
        float ev[8] = { a0.x, a0.y, a0.z, a0.w, a1.x, a1.y, a1.z, a1.w };
        float od[8] = { b0.x, b0.y, b0.z, b0.w, b1.x, b1.y, b1.z, b1.w };
#pragma unroll
        for (int j = 0; j < 8; j++) {
            const int n = c8 * 8 + j;
            unsigned int v = (unsigned int)f2bf(ev[j]) | ((unsigned int)f2bf(od[j]) << 16);
            P[n * 32 + (rp ^ ((n >> 3) << 2))] = v;
        }
    }
    __syncthreads();
    {
        const int n0 = t >> 3;            // 0..31
        const int q  = t & 7;             // k-octet 0..7
#pragma unroll
        for (int p = 0; p < 2; p++) {
            const int n = n0 + 32 * p;
            uint4 v = *(const uint4*)&P[n * 32 + 4 * (q ^ (n >> 3))];
            *(uint4*)&dst[n * 64 + q * 8] = v;   // sequential: thread t -> offset t*16B
        }
    }
}

// ---------------- GEMM1: 256 thr, 4 waves 2x2, wave tile 64x32 ----------------
__global__ __launch_bounds__(256, 2) void k_gemm1(
    const unsigned short* __restrict__ xb,
    const unsigned short* __restrict__ w1t, const unsigned short* __restrict__ w3t,
    const int* __restrict__ counts, const int* __restrict__ basep,
    const int* __restrict__ rowmap, unsigned short* __restrict__ act)
{
    const int e = blockIdx.z;
    const int nrows = counts[e];
    const int m0 = blockIdx.y * BM;
    if (m0 >= nrows) return;
    const int f0 = blockIdx.x * BN1;
    const int gbase = basep[e];

    __shared__ __align__(16) unsigned short At[2][BM][BK];
    __shared__ __align__(16) unsigned short B1[2][BN1][BK];
    __shared__ __align__(16) unsigned short B3[2][BN1][BK];

    const int t = threadIdx.x;
    const int lane = t & 63;
    const int w = t >> 6;                 // 0..3
    const int wrm = w >> 1, wnn = w & 1;  // 2x2 wave grid; wave tile 64 x 32
    const int lr = lane >> 3;
    const int so = ((lane & 7) ^ lr) * 8; // verified swizzle: chunk ^ (row&7)

    const unsigned short* asrc[4];
#pragma unroll
    for (int c = 0; c < 4; c++) {
        const int row = (w * 4 + c) * 8 + lr;
        const int tok = rowmap[gbase + min(m0 + row, nrows - 1)];
        asrc[c] = xb + (size_t)tok * HD + so;
    }
    // B: tile-contiguous layout; ftile = blockIdx.x (BN1==64). Per k-step the
    // whole staged tile is one contiguous 8KB block at + it*TSZ.
    const unsigned short* b1src[2];
    const unsigned short* b3src[2];
#pragma unroll
    for (int c = 0; c < 2; c++) {
        const int row = (w * 2 + c) * 8 + lr;
        const size_t tb = (size_t)e * HD * FD + ((size_t)blockIdx.x * 16) * TSZ + row * 64 + so;
        b1src[c] = w1t + tb;
        b3src[c] = w3t + tb;
    }

    f32x4 acc1[4][2], acc3[4][2];
#pragma unroll
    for (int i = 0; i < 4; i++)
#pragma unroll
        for (int j = 0; j < 2; j++) { acc1[i][j] = (f32x4)(0.f); acc3[i][j] = (f32x4)(0.f); }

    const int l15 = lane & 15;
    const int lhi = lane >> 4;
    const int rs = (l15 & 7) * 8;

    // prologue: stage k-tile 0 into buf 0 (8 loads/thread in flight)
#pragma unroll
    for (int c = 0; c < 4; c++) gl16(asrc[c], &At[0][(w * 4 + c) * 8][0]);
#pragma unroll
    for (int c = 0; c < 2; c++) {
        gl16(b1src[c], &B1[0][(w * 2 + c) * 8][0]);
        gl16(b3src[c], &B3[0][(w * 2 + c) * 8][0]);
    }

    for (int it = 0; it < NIT1; ++it) {
        const int cur = it & 1;
        if (it + 1 < NIT1) {
            const int kn = (it + 1) * BK;          // A offset (row-major xb)
            const size_t bt = (size_t)(it + 1) * TSZ;  // B offset (tile-contiguous)
#pragma unroll
            for (int c = 0; c < 4; c++) gl16(asrc[c] + kn, &At[cur ^ 1][(w * 4 + c) * 8][0]);
#pragma unroll
            for (int c = 0; c < 2; c++) {
                gl16(b1src[c] + bt, &B1[cur ^ 1][(w * 2 + c) * 8][0]);
                gl16(b3src[c] + bt, &B3[cur ^ 1][(w * 2 + c) * 8][0]);
            }
            asm volatile("s_waitcnt vmcnt(8)" ::: "memory");   // wait current tile only
        } else {
            asm volatile("s_waitcnt vmcnt(0)" ::: "memory");
        }
        __builtin_amdgcn_s_barrier();
#pragma unroll
        for (int kk = 0; kk < 2; kk++) {
            const int kc = (kk * 32 + lhi * 8) ^ rs;
            short8 af[4], b1f[2], b3f[2];
#pragma unroll
            for (int i = 0; i < 4; i++)
                af[i] = *(const short8*)&At[cur][wrm * 64 + i * 16 + l15][kc];
#pragma unroll
            for (int j = 0; j < 2; j++) {
                b1f[j] = *(const short8*)&B1[cur][wnn * 32 + j * 16 + l15][kc];
                b3f[j] = *(const short8*)&B3[cur][wnn * 32 + j * 16 + l15][kc];
            }
#pragma unroll
            for (int i = 0; i < 4; i++)
#pragma unroll
                for (int j = 0; j < 2; j++) {
                    acc1[i][j] = __builtin_amdgcn_mfma_f32_16x16x32_bf16(af[i], b1f[j], acc1[i][j], 0, 0, 0);
                    acc3[i][j] = __builtin_amdgcn_mfma_f32_16x16x32_bf16(af[i], b3f[j], acc3[i][j], 0, 0, 0);
                }
        }
        __builtin_amdgcn_s_barrier();
    }

    // epilogue: SwiGLU, bf16 act
    const int rbase = wrm * 64 + lhi * 4;
    const int cbase = f0 + wnn * 32 + l15;
#pragma unroll
    for (int i = 0; i < 4; i++) {
#pragma unroll
        for (int r = 0; r < 4; r++) {
            const int ml = rbase + i * 16 + r;
            if (m0 + ml < nrows) {
                const size_t rowoff = (size_t)(gbase + m0 + ml) * FD;
#pragma unroll
                for (int j = 0; j < 2; j++) {
                    float y1 = acc1[i][j][r];
                    float y3 = acc3[i][j][r];
                    float sv = (y1 / (1.f + __expf(-y1))) * y3;
                    act[rowoff + cbase + j * 16] = f2bf(sv);
                }
            }
        }
    }
}

// ---------------- GEMM2: BM2=64 x BN=128, wave tile 32x64, K-split x2 ----------------
// Epilogue atomically accumulates into out (r17-neutral, keeps ws small).
__global__ __launch_bounds__(256, 4) void k_gemm2(
    const unsigned short* __restrict__ act,
    const unsigned short* __restrict__ w2t,
    const int* __restrict__ counts, const int* __restrict__ basep,
    const int* __restrict__ rowmap, const int* __restrict__ rowk,
    const float* __restrict__ roww, float* __restrict__ out)
{
    const int z = blockIdx.z;
    const int e = z >> 1, ks = z & 1;
    const int nrows = counts[e];
    const int m0 = blockIdx.y * BM2;
    if (m0 >= nrows) return;
    const int h0 = blockIdx.x * BN;
    const int gbase = basep[e];
    const int kbase = ks * KLEN2;

    __shared__ __align__(16) unsigned short At[2][BM2][BK];
    __shared__ __align__(16) unsigned short Bt[2][BN][BK];

    const int t = threadIdx.x;
    const int lane = t & 63;
    const int w = t >> 6;                 // 0..3
    const int wr2 = w >> 1, wn2 = w & 1;  // 2x2; wave tile 32 x 64
    const int lr = lane >> 3;
    const int so = ((lane & 7) ^ lr) * 8;

    const unsigned short* asrc[2];
#pragma unroll
    for (int c = 0; c < 2; c++) {
        const int row = (w * 2 + c) * 8 + lr;
        asrc[c] = act + ((size_t)gbase + min(m0 + row, nrows - 1)) * FD + so + kbase;
    }
    // B: tile-contiguous w2t; ntile = h0/64 + (row>>6); k-split offset ks*28 tiles.
    const unsigned short* bsrc[4];
#pragma unroll
    for (int c = 0; c < 4; c++) {
        const int row = (w * 4 + c) * 8 + lr;
        const int ntile = (h0 >> 6) + (row >> 6);
        bsrc[c] = w2t + (size_t)e * HD * FD + ((size_t)ntile * 56 + ks * 28) * TSZ
                + (row & 63) * 64 + so;
    }

    f32x4 acc[2][4];
#pragma unroll
    for (int i = 0; i < 2; i++)
#pragma unroll
        for (int j = 0; j < 4; j++) acc[i][j] = (f32x4)(0.f);

    const int l15 = lane & 15;
    const int lhi = lane >> 4;
    const int rs = (l15 & 7) * 8;

    // prologue: stage tile 0 into buf 0 (6 loads/thread)
#pragma unroll
    for (int c = 0; c < 2; c++) gl16(asrc[c], &At[0][(w * 2 + c) * 8][0]);
#pragma unroll
    for (int c = 0; c < 4; c++) gl16(bsrc[c], &Bt[0][(w * 4 + c) * 8][0]);

    for (int it = 0; it < NIT2; ++it) {
        const int cur = it & 1;
        if (it + 1 < NIT2) {
            const int kn = (it + 1) * BK;
            const size_t bt = (size_t)(it + 1) * TSZ;
#pragma unroll
            for (int c = 0; c < 2; c++) gl16(asrc[c] + kn, &At[cur ^ 1][(w * 2 + c) * 8][0]);
#pragma unroll
            for (int c = 0; c < 4; c++) gl16(bsrc[c] + bt, &Bt[cur ^ 1][(w * 4 + c) * 8][0]);
            asm volatile("s_waitcnt vmcnt(6)" ::: "memory");
        } else {
            asm volatile("s_waitcnt vmcnt(0)" ::: "memory");
        }
        __builtin_amdgcn_s_barrier();
#pragma unroll
        for (int kk = 0; kk < 2; kk++) {
            const int kc = (kk * 32 + lhi * 8) ^ rs;
            short8 af[2], bf[4];
#pragma unroll
            for (int i = 0; i < 2; i++)
                af[i] = *(const short8*)&At[cur][wr2 * 32 + i * 16 + l15][kc];
#pragma unroll
            for (int j = 0; j < 4; j++)
                bf[j] = *(const short8*)&Bt[cur][wn2 * 64 + j * 16 + l15][kc];
#pragma unroll
            for (int i = 0; i < 2; i++)
#pragma unroll
                for (int j = 0; j < 4; j++)
                    acc[i][j] = __builtin_amdgcn_mfma_f32_16x16x32_bf16(af[i], bf[j], acc[i][j], 0, 0, 0);
        }
        __builtin_amdgcn_s_barrier();
    }

    const int rbase = wr2 * 32 + lhi * 4;
    const int cbase = h0 + wn2 * 64 + l15;
#pragma unroll
    for (int i = 0; i < 2; i++) {
#pragma unroll
        for (int r = 0; r < 4; r++) {
            const int ml = rbase + i * 16 + r;
            if (m0 + ml < nrows) {
                const int grow = gbase + m0 + ml;
                const int tok = rowmap[grow];
                const float wv = roww[grow];
                float* op = out + (size_t)tok * HD + cbase;
#pragma unroll
                for (int j = 0; j < 4; j++)
                    atomicAdd(&op[j * 16], acc[i][j][r] * wv);
            }
        }
    }
}

extern "C" void kernel_launch(void* const* d_in, const int* in_sizes, int n_in,
                              void* d_out, int out_size, void* d_ws, size_t ws_size,
                              hipStream_t stream) {
    const float* x  = (const float*)d_in[0];
    const float* gw = (const float*)d_in[1];
    const float* w1 = (const float*)d_in[2];
    const float* w3 = (const float*)d_in[3];
    const float* w2 = (const float*)d_in[4];
    float* out = (float*)d_out;

    char* ws = (char*)d_ws;
    size_t off = 0;
    auto alloc = [&](size_t b) { char* p = ws + off; off += (b + 255) & ~(size_t)255; return p; };
    int*   sel    = (int*)  alloc((size_t)NTOK * 2 * 4);
    float* selw   = (float*)alloc((size_t)NTOK * 2 * 4);
    int*   counts = (int*)  alloc(NE * 4);
    int*   basep  = (int*)  alloc(NE * 4);
    int*   fillc  = (int*)  alloc(NE * 4);
    int*   rowmap = (int*)  alloc((size_t)NTOK * 2 * 4);
    int*   rowk   = (int*)  alloc((size_t)NTOK * 2 * 4);
    float* roww   = (float*)alloc((size_t)NTOK * 2 * 4);
    unsigned short* xb  = (unsigned short*)alloc((size_t)NTOK * HD * 2);
    unsigned short* act = (unsigned short*)alloc((size_t)NTOK * 2 * FD * 2);
    unsigned short* w1t = (unsigned short*)alloc((size_t)NE * HD * FD * 2);
    unsigned short* w3t = (unsigned short*)alloc((size_t)NE * HD * FD * 2);
    unsigned short* w2t = (unsigned short*)alloc((size_t)NE * HD * FD * 2);

    hipMemsetAsync(counts, 0, NE * 4, stream);
    hipMemsetAsync(out, 0, (size_t)out_size * 4, stream);   // gemm2 accumulates atomically
    k_wt3<<<dim3(896, 1, 24), 256, 0, stream>>>(w1, w3, w2, w1t, w3t, w2t);
    k_cvt<<<(NTOK * HD) / (256 * 8), 256, 0, stream>>>(x, xb);
    k_router<<<NTOK / 4, 256, 0, stream>>>(x, gw, sel, selw, counts);
    k_scan<<<1, 64, 0, stream>>>(counts, basep, fillc);
    k_fill<<<NTOK / 256, 256, 0, stream>>>(sel, selw, basep, fillc, rowmap, rowk, roww);
    k_gemm1<<<dim3(FD / BN1, NTOK / BM, NE), 256, 0, stream>>>(xb, w1t, w3t, counts, basep, rowmap, act);
    k_gemm2<<<dim3(HD / BN, NTOK / BM2, NE * KS2), 256, 0, stream>>>(act, w2t, counts, basep, rowmap, rowk, roww, out);
}